// Round 17
// baseline (270.430 us; speedup 1.0000x reference)
//
#include <hip/hip_runtime.h>

typedef __attribute__((ext_vector_type(8))) short bf16x8;
typedef __attribute__((ext_vector_type(4))) short s16x4;
typedef __attribute__((ext_vector_type(16))) float f32x16;

#define LOG2E 1.4426950408889634f
#define MASKV2 (-1442695.0f)          // -1e6 * log2(e): exp2 domain

__device__ __forceinline__ unsigned cvt_pk_bf16(float lo, float hi_) {
  unsigned r;
  asm("v_cvt_pk_bf16_f32 %0, %1, %2" : "=v"(r) : "v"(lo), "v"(hi_));
  return r;
}

// Fast mask-dtype detect: coalesced uint4 reads over the first 64KB.
// int32 0/1 arrays have zero bytes at offsets %4!=0; uint8 0/1 arrays don't.
__global__ void detect_mask_kernel(const unsigned char* __restrict__ m, int* flag) {
  __shared__ unsigned s[64];
  const int tid = threadIdx.x;
  unsigned acc = 0;
  const uint4* p = (const uint4*)m;
#pragma unroll
  for (int i = 0; i < 16; ++i) {
    uint4 a = p[tid + i * 256];
    acc |= (a.x | a.y | a.z | a.w) & 0xFFFFFF00u;
  }
  acc = acc | (unsigned)__shfl_xor((int)acc, 1);
  acc = acc | (unsigned)__shfl_xor((int)acc, 2);
  acc = acc | (unsigned)__shfl_xor((int)acc, 4);
  acc = acc | (unsigned)__shfl_xor((int)acc, 8);
  acc = acc | (unsigned)__shfl_xor((int)acc, 16);
  acc = acc | (unsigned)__shfl_xor((int)acc, 32);
  if ((tid & 63) == 0) s[tid >> 6] = acc;
  __syncthreads();
  if (tid == 0) flag[0] = ((s[0] | s[1] | s[2] | s[3]) != 0) ? 1 : 0;
}

// Round-17: r13's winning config (256t blocks, 2/CU drift, dbuf LDS) with
// staging FUSED back in (no image pre-pass): K-f32 loads issued at iter top
// (QK covers latency), converted after QK; V-f32 loads issued after that
// (softmax/PV covers), converted after PV. One barrier per tile.
// K/V-stage register live ranges don't overlap (peak ~220 VGPR, no spill).
__global__ __launch_bounds__(256, 2)
void attn17(const float* __restrict__ Qp, const float* __restrict__ Kp,
            const float* __restrict__ Vp, const unsigned char* __restrict__ M8,
            float* __restrict__ Op, const int* __restrict__ flag)
{
  const int tid  = threadIdx.x;
  const int lane = tid & 63;
  const int wv   = tid >> 6;        // 0..3
  const int hi   = lane >> 5;
  const int l31  = lane & 31;
  const int n    = blockIdx.x;      // 512 blocks
  const int b    = (n & 7) + 8 * (n >> 7);   // XCD-aware, bijective
  const int qt   = (n >> 3) & 15;
  const int q    = qt * 128 + wv * 32 + l31;
  const bool is8 = (flag[0] != 0);

  __shared__ __align__(16) short Kl[2][64 * 128];   // K tiles, XOR-swizzled
  __shared__ __align__(16) short Vt[2][128 * 64];   // V^T tiles, XOR-swizzled

  // ---- Q B-frags (col=q=lane&31, k-dim=d=dc*16+hi*8+j), scale*log2e folded ----
  const float qscale = 0.08838834764831845f * LOG2E;
  bf16x8 qf[8];
  {
    const float* qrow = Qp + ((size_t)b * 2048 + q) * 128;
#pragma unroll
    for (int dc = 0; dc < 8; ++dc) {
      const int d0 = dc * 16 + hi * 8;
      float4 x = *(const float4*)(qrow + d0);
      float4 y = *(const float4*)(qrow + d0 + 4);
      union { bf16x8 v; unsigned u[4]; } uu;
      uu.u[0] = cvt_pk_bf16(x.x * qscale, x.y * qscale);
      uu.u[1] = cvt_pk_bf16(x.z * qscale, x.w * qscale);
      uu.u[2] = cvt_pk_bf16(y.x * qscale, y.y * qscale);
      uu.u[3] = cvt_pk_bf16(y.z * qscale, y.w * qscale);
      qf[dc] = uu.v;
    }
  }

  f32x16 oacc[4];
#pragma unroll
  for (int gg = 0; gg < 4; ++gg)
#pragma unroll
    for (int r = 0; r < 16; ++r) oacc[gg][r] = 0.f;

  float mrun = -1e30f, lrun = 0.f;
  const unsigned char* mrow8  = M8 + ((size_t)b * 2048 + q) * (size_t)2048;
  const int*           mrow32 = (const int*)M8 + ((size_t)b * 2048 + q) * (size_t)2048;
  const int xk = 8 * (l31 & 15);
  const int xv = 8 * (l31 >> 2);
  const size_t kvrow0 = (size_t)b * 2048 * 128;

  // Staging geometry (256 threads):
  //   K: row = (tid>>5) + 8i (i<8), col = (tid&31)*4  -> 8 float4/thread
  //   V: d-block db = tid&31; k-blocks kb+8g (g<2), 4 rows x 1 float4 each
  const int krow0 = tid >> 5, kcol0 = (tid & 31) * 4;
  const int db = tid & 31, kb = tid >> 5;

#define K_LOAD(t_, kreg_)                                                             \
  do {                                                                                 \
    const size_t nb_ = kvrow0 + (size_t)(t_) * 64 * 128;                               \
    _Pragma("unroll")                                                                  \
    for (int i_ = 0; i_ < 8; ++i_)                                                     \
      (kreg_)[i_] = *(const float4*)(Kp + nb_ + (krow0 + i_ * 8) * 128 + kcol0);       \
  } while (0)

#define K_WRITE(buf_, kreg_)                                                           \
  do {                                                                                  \
    short* kd_ = &Kl[buf_][0];                                                          \
    _Pragma("unroll")                                                                   \
    for (int i_ = 0; i_ < 8; ++i_) {                                                    \
      const int row_ = krow0 + i_ * 8;                                                  \
      union { s16x4 v; unsigned u[2]; } pk_;                                            \
      pk_.u[0] = cvt_pk_bf16((kreg_)[i_].x, (kreg_)[i_].y);                             \
      pk_.u[1] = cvt_pk_bf16((kreg_)[i_].z, (kreg_)[i_].w);                             \
      *(s16x4*)&kd_[row_ * 128 + (kcol0 ^ (8 * (row_ & 15)))] = pk_.v;                  \
    }                                                                                   \
  } while (0)

#define V_LOAD(t_, vreg_)                                                               \
  do {                                                                                   \
    const size_t nb_ = kvrow0 + (size_t)(t_) * 64 * 128;                                 \
    _Pragma("unroll")                                                                    \
    for (int g_ = 0; g_ < 2; ++g_) {                                                     \
      const int k0_ = (kb + 8 * g_) * 4;                                                 \
      _Pragma("unroll")                                                                  \
      for (int i_ = 0; i_ < 4; ++i_)                                                     \
        (vreg_)[g_ * 4 + i_] = *(const float4*)(Vp + nb_ + (k0_ + i_) * 128 + db * 4);   \
    }                                                                                    \
  } while (0)

#define V_WRITE(buf_, vreg_)                                                             \
  do {                                                                                    \
    short* vd_ = &Vt[buf_][0];                                                            \
    _Pragma("unroll")                                                                     \
    for (int g_ = 0; g_ < 2; ++g_) {                                                      \
      const int k0_ = (kb + 8 * g_) * 4;                                                  \
      const int cs_ = k0_ ^ (8 * (db & 7));                                               \
      union { float4 v; float f[4]; } a0_, a1_, a2_, a3_;                                 \
      a0_.v = (vreg_)[g_ * 4 + 0]; a1_.v = (vreg_)[g_ * 4 + 1];                           \
      a2_.v = (vreg_)[g_ * 4 + 2]; a3_.v = (vreg_)[g_ * 4 + 3];                           \
      _Pragma("unroll")                                                                   \
      for (int j_ = 0; j_ < 4; ++j_) {                                                    \
        union { s16x4 v; unsigned u[2]; } pk_;                                            \
        pk_.u[0] = cvt_pk_bf16(a0_.f[j_], a1_.f[j_]);                                     \
        pk_.u[1] = cvt_pk_bf16(a2_.f[j_], a3_.f[j_]);                                     \
        *(s16x4*)&vd_[(db * 4 + j_) * 64 + cs_] = pk_.v;                                  \
      }                                                                                   \
    }                                                                                     \
  } while (0)

  // ---- prologue: stage tile 0 into buf 0 ----
  {
    float4 kreg[8];
    K_LOAD(0, kreg);
    K_WRITE(0, kreg);
    float4 vreg[8];
    V_LOAD(0, vreg);
    V_WRITE(0, vreg);
  }
  __syncthreads();

  for (int kt = 0; kt < 32; ++kt) {
    const int cur = kt & 1;

    // ---- issue next K tile's f32 loads (QK below covers the latency) ----
    float4 kreg[8];
    if (kt < 31) K_LOAD(kt + 1, kreg);

    // ---- this tile's mask dwords ----
    unsigned mg[8];
    if (is8) {
#pragma unroll
      for (int m = 0; m < 4; ++m) {
        mg[m]     = *(const unsigned*)(mrow8 + kt * 64 + hi * 4 + m * 8);
        mg[4 + m] = *(const unsigned*)(mrow8 + kt * 64 + 32 + hi * 4 + m * 8);
      }
    }

    // ---- S^T = K · Q^T (swapped): lane holds S[k][q=l31] ----
    f32x16 s0m, s1m;
#pragma unroll
    for (int r = 0; r < 16; ++r) { s0m[r] = 0.f; s1m[r] = 0.f; }
    __builtin_amdgcn_s_setprio(1);
#pragma unroll
    for (int dc = 0; dc < 8; ++dc) {
      const int colb = (dc * 16 + hi * 8) ^ xk;
      bf16x8 a0 = *(const bf16x8*)&Kl[cur][l31 * 128 + colb];
      bf16x8 a1 = *(const bf16x8*)&Kl[cur][(32 + l31) * 128 + colb];
      s0m = __builtin_amdgcn_mfma_f32_32x32x16_bf16(a0, qf[dc], s0m, 0, 0, 0);
      s1m = __builtin_amdgcn_mfma_f32_32x32x16_bf16(a1, qf[dc], s1m, 0, 0, 0);
    }
    __builtin_amdgcn_s_setprio(0);

    // ---- convert+write next K into buf^1 (frees kreg); issue V loads ----
    float4 vreg[8];
    if (kt < 31) {
      K_WRITE(cur ^ 1, kreg);
      V_LOAD(kt + 1, vreg);   // covered by mask/softmax/redistribute/PV below
    }

    // ---- mask: reg r <-> k = 32*kk + (r&3) + 8*(r>>2) + 4*hi ----
    if (is8) {
#pragma unroll
      for (int m = 0; m < 4; ++m)
#pragma unroll
        for (int e = 0; e < 4; ++e) {
          s0m[4 * m + e] = ((mg[m]     >> (8 * e)) & 0xffu) ? MASKV2 : s0m[4 * m + e];
          s1m[4 * m + e] = ((mg[4 + m] >> (8 * e)) & 0xffu) ? MASKV2 : s1m[4 * m + e];
        }
    } else {
#pragma unroll
      for (int m = 0; m < 4; ++m) {
        int4 w0 = *(const int4*)(mrow32 + kt * 64 + hi * 4 + m * 8);
        int4 w1 = *(const int4*)(mrow32 + kt * 64 + 32 + hi * 4 + m * 8);
        s0m[4 * m + 0] = w0.x ? MASKV2 : s0m[4 * m + 0];
        s0m[4 * m + 1] = w0.y ? MASKV2 : s0m[4 * m + 1];
        s0m[4 * m + 2] = w0.z ? MASKV2 : s0m[4 * m + 2];
        s0m[4 * m + 3] = w0.w ? MASKV2 : s0m[4 * m + 3];
        s1m[4 * m + 0] = w1.x ? MASKV2 : s1m[4 * m + 0];
        s1m[4 * m + 1] = w1.y ? MASKV2 : s1m[4 * m + 1];
        s1m[4 * m + 2] = w1.z ? MASKV2 : s1m[4 * m + 2];
        s1m[4 * m + 3] = w1.w ? MASKV2 : s1m[4 * m + 3];
      }
    }

    // ---- online softmax (tree in-lane + verified shfl cross-half) ----
    float v[16];
#pragma unroll
    for (int r = 0; r < 16; ++r) v[r] = fmaxf(s0m[r], s1m[r]);
#pragma unroll
    for (int st = 8; st > 0; st >>= 1)
#pragma unroll
      for (int r = 0; r < 8; ++r)
        if (r < st) v[r] = fmaxf(v[r], v[r + st]);
    float tm = fmaxf(v[0], __shfl_xor(v[0], 32));

    if (__any(tm > mrun + 8.0f)) {        // defer-max (T13)
      float mnew = fmaxf(mrun, tm);
      float corr = __builtin_amdgcn_exp2f(mrun - mnew);
      mrun = mnew; lrun *= corr;
#pragma unroll
      for (int gg = 0; gg < 4; ++gg)
#pragma unroll
        for (int r = 0; r < 16; ++r) oacc[gg][r] *= corr;
    }

#pragma unroll
    for (int r = 0; r < 16; ++r) s0m[r] = __builtin_amdgcn_exp2f(s0m[r] - mrun);
#pragma unroll
    for (int r = 0; r < 16; ++r) s1m[r] = __builtin_amdgcn_exp2f(s1m[r] - mrun);
    float w[16];
#pragma unroll
    for (int r = 0; r < 16; ++r) w[r] = s0m[r] + s1m[r];
#pragma unroll
    for (int st = 8; st > 0; st >>= 1)
#pragma unroll
      for (int r = 0; r < 8; ++r)
        if (r < st) w[r] += w[r + st];
    lrun += w[0] + __shfl_xor(w[0], 32);

    // ---- P (S^T C-layout) -> P^T B-frags (verified shfl path) ----
    unsigned pk0[8], pk1[8];
#pragma unroll
    for (int i = 0; i < 8; ++i) {
      pk0[i] = cvt_pk_bf16(s0m[2 * i], s0m[2 * i + 1]);
      pk1[i] = cvt_pk_bf16(s1m[2 * i], s1m[2 * i + 1]);
    }
    bf16x8 pa[4];
#pragma unroll
    for (int ks = 0; ks < 4; ++ks) {
      const int base = 4 * (ks & 1);
      unsigned o0, o1, sd0, sd1;
      if (ks < 2) {
        o0  = hi ? pk0[base + 2] : pk0[base + 0];
        o1  = hi ? pk0[base + 3] : pk0[base + 1];
        sd0 = hi ? pk0[base + 0] : pk0[base + 2];
        sd1 = hi ? pk0[base + 1] : pk0[base + 3];
      } else {
        o0  = hi ? pk1[base + 2] : pk1[base + 0];
        o1  = hi ? pk1[base + 3] : pk1[base + 1];
        sd0 = hi ? pk1[base + 0] : pk1[base + 2];
        sd1 = hi ? pk1[base + 1] : pk1[base + 3];
      }
      unsigned rec0 = (unsigned)__shfl_xor((int)sd0, 32);
      unsigned rec1 = (unsigned)__shfl_xor((int)sd1, 32);
      union { bf16x8 v; unsigned u[4]; } uu;
      uu.u[0] = hi ? rec0 : o0;
      uu.u[1] = hi ? rec1 : o1;
      uu.u[2] = hi ? o0 : rec0;
      uu.u[3] = hi ? o1 : rec1;
      pa[ks] = uu.v;
    }

    // ---- O^T += V^T · P^T ----
    __builtin_amdgcn_s_setprio(1);
#pragma unroll
    for (int gg = 0; gg < 4; ++gg) {
      const int drow = gg * 32 + l31;
#pragma unroll
      for (int ks = 0; ks < 4; ++ks) {
        bf16x8 va = *(const bf16x8*)&Vt[cur][drow * 64 + ((ks * 16 + hi * 8) ^ xv)];
        oacc[gg] = __builtin_amdgcn_mfma_f32_32x32x16_bf16(va, pa[ks], oacc[gg], 0, 0, 0);
      }
    }
    __builtin_amdgcn_s_setprio(0);

    // ---- convert+write next V into buf^1 ----
    if (kt < 31) V_WRITE(cur ^ 1, vreg);

    __syncthreads();   // staged writes visible; all reads of buf cur done
  }
#undef K_LOAD
#undef K_WRITE
#undef V_LOAD
#undef V_WRITE

  // ---- epilogue: O[q][d] = oacc/l; d = 32gg + 4hi + 8m + e ----
  const float inv = 1.0f / lrun;
  float* orow = Op + ((size_t)b * 2048 + q) * 128;
#pragma unroll
  for (int gg = 0; gg < 4; ++gg) {
#pragma unroll
    for (int m = 0; m < 4; ++m) {
      float4 o;
      o.x = oacc[gg][4 * m + 0] * inv;
      o.y = oacc[gg][4 * m + 1] * inv;
      o.z = oacc[gg][4 * m + 2] * inv;
      o.w = oacc[gg][4 * m + 3] * inv;
      *(float4*)(orow + gg * 32 + hi * 4 + m * 8) = o;
    }
  }
}

extern "C" void kernel_launch(void* const* d_in, const int* in_sizes, int n_in,
                              void* d_out, int out_size, void* d_ws, size_t ws_size,
                              hipStream_t stream) {
  const float* qp = (const float*)d_in[0];
  const float* kp = (const float*)d_in[1];
  const float* vp = (const float*)d_in[2];
  const unsigned char* mp = (const unsigned char*)d_in[3];
  float* op = (float*)d_out;
  int* flag = (int*)d_ws;

  detect_mask_kernel<<<1, 256, 0, stream>>>(mp, flag);
  attn17<<<512, 256, 0, stream>>>(qp, kp, vp, mp, op, flag);
}

// Round 18
// 202.011 us; speedup vs baseline: 1.3387x; 1.3387x over previous
//
#include <hip/hip_runtime.h>

typedef __attribute__((ext_vector_type(8))) short bf16x8;
typedef __attribute__((ext_vector_type(4))) short s16x4;
typedef __attribute__((ext_vector_type(16))) float f32x16;

#define LOG2E 1.4426950408889634f
#define MASKV2 (-1442695.0f)          // -1e6 * log2(e): exp2 domain
#define GAS __attribute__((address_space(1)))
#define LAS __attribute__((address_space(3)))

__device__ __forceinline__ unsigned cvt_pk_bf16(float lo, float hi_) {
  unsigned r;
  asm("v_cvt_pk_bf16_f32 %0, %1, %2" : "=v"(r) : "v"(lo), "v"(hi_));
  return r;
}

// Fast mask-dtype detect: coalesced uint4 reads over the first 64KB.
// int32 0/1 arrays have zero bytes at offsets %4!=0; uint8 0/1 arrays don't.
__global__ void detect_mask_kernel(const unsigned char* __restrict__ m, int* flag) {
  __shared__ unsigned s[64];
  const int tid = threadIdx.x;
  unsigned acc = 0;
  const uint4* p = (const uint4*)m;
#pragma unroll
  for (int i = 0; i < 16; ++i) {
    uint4 a = p[tid + i * 256];
    acc |= (a.x | a.y | a.z | a.w) & 0xFFFFFF00u;
  }
  acc = acc | (unsigned)__shfl_xor((int)acc, 1);
  acc = acc | (unsigned)__shfl_xor((int)acc, 2);
  acc = acc | (unsigned)__shfl_xor((int)acc, 4);
  acc = acc | (unsigned)__shfl_xor((int)acc, 8);
  acc = acc | (unsigned)__shfl_xor((int)acc, 16);
  acc = acc | (unsigned)__shfl_xor((int)acc, 32);
  if ((tid & 63) == 0) s[tid >> 6] = acc;
  __syncthreads();
  if (tid == 0) flag[0] = ((s[0] | s[1] | s[2] | s[3]) != 0) ? 1 : 0;
}

// Build per-(b,kt) bf16 tile images: 16 KB swizzled K + 16 KB swizzled V^T,
// byte-identical to the attn kernel's LDS layout (linear DMA staging).
__global__ __launch_bounds__(512)
void build_images(const float* __restrict__ Kp, const float* __restrict__ Vp,
                  char* __restrict__ img)
{
  const int tid  = threadIdx.x;
  const int tile = blockIdx.x;          // b*32 + kt
  const int b = tile >> 5, kt = tile & 31;
  __shared__ __align__(16) short Kl[64 * 128];
  __shared__ __align__(16) short Vt[128 * 64];
  const size_t kvbase = ((size_t)b * 2048 + (size_t)kt * 64) * 128;

  const int krow0 = tid >> 5, kcol0 = (tid & 31) * 4;
#pragma unroll
  for (int i = 0; i < 4; ++i) {
    const int row = krow0 + i * 16;
    float4 x = *(const float4*)(Kp + kvbase + row * 128 + kcol0);
    union { s16x4 v; unsigned u[2]; } pk;
    pk.u[0] = cvt_pk_bf16(x.x, x.y);
    pk.u[1] = cvt_pk_bf16(x.z, x.w);
    *(s16x4*)&Kl[row * 128 + (kcol0 ^ (8 * (row & 15)))] = pk.v;
  }
  {
    const int db = tid & 31, kb = tid >> 5;
    union { float4 v; float f[4]; } r0, r1, r2, r3;
    r0.v = *(const float4*)(Vp + kvbase + (kb * 4 + 0) * 128 + db * 4);
    r1.v = *(const float4*)(Vp + kvbase + (kb * 4 + 1) * 128 + db * 4);
    r2.v = *(const float4*)(Vp + kvbase + (kb * 4 + 2) * 128 + db * 4);
    r3.v = *(const float4*)(Vp + kvbase + (kb * 4 + 3) * 128 + db * 4);
    const int cs = (kb * 4) ^ (8 * (db & 7));
#pragma unroll
    for (int j = 0; j < 4; ++j) {
      union { s16x4 v; unsigned u[2]; } pk;
      pk.u[0] = cvt_pk_bf16(r0.f[j], r1.f[j]);
      pk.u[1] = cvt_pk_bf16(r2.f[j], r3.f[j]);
      *(s16x4*)&Vt[(db * 4 + j) * 64 + cs] = pk.v;
    }
  }
  __syncthreads();
  char* o = img + (size_t)tile * 32768;
  *(uint4*)(o +     0 + tid * 16) = *(const uint4*)((const char*)Kl +    0 + tid * 16);
  *(uint4*)(o +  8192 + tid * 16) = *(const uint4*)((const char*)Kl + 8192 + tid * 16);
  *(uint4*)(o + 16384 + tid * 16) = *(const uint4*)((const char*)Vt +    0 + tid * 16);
  *(uint4*)(o + 24576 + tid * 16) = *(const uint4*)((const char*)Vt + 8192 + tid * 16);
}

// Round-18: revert to r16 (best measured: 202.1 us total).
// 256t blocks, 2 independent blocks/CU (drift), 2-slot K/V rings, DMA
// staging from images, QK-one-ahead, prologue race barrier.
__global__ __launch_bounds__(256, 2)
void attn18(const float* __restrict__ Qp, const unsigned char* __restrict__ M8,
            const char* __restrict__ img, float* __restrict__ Op,
            const int* __restrict__ flag)
{
  const int tid  = threadIdx.x;
  const int lane = tid & 63;
  const int wv   = tid >> 6;        // 0..3
  const int hi   = lane >> 5;
  const int l31  = lane & 31;
  const int n    = blockIdx.x;      // 512 blocks
  const int b    = (n & 7) + 8 * (n >> 7);   // XCD-aware, bijective
  const int qt   = (n >> 3) & 15;
  const int q    = qt * 128 + wv * 32 + l31;
  const bool is8 = (flag[0] != 0);

  __shared__ __align__(16) short Kl[2][64 * 128];   // K ring (32KB)
  __shared__ __align__(16) short Vt[2][128 * 64];   // V^T ring (32KB)

  // ---- Q B-frags (col=q=lane&31, k-dim=d=dc*16+hi*8+j), scale*log2e folded ----
  const float qscale = 0.08838834764831845f * LOG2E;
  bf16x8 qf[8];
  {
    const float* qrow = Qp + ((size_t)b * 2048 + q) * 128;
#pragma unroll
    for (int dc = 0; dc < 8; ++dc) {
      const int d0 = dc * 16 + hi * 8;
      float4 x = *(const float4*)(qrow + d0);
      float4 y = *(const float4*)(qrow + d0 + 4);
      union { bf16x8 v; unsigned u[4]; } uu;
      uu.u[0] = cvt_pk_bf16(x.x * qscale, x.y * qscale);
      uu.u[1] = cvt_pk_bf16(x.z * qscale, x.w * qscale);
      uu.u[2] = cvt_pk_bf16(y.x * qscale, y.y * qscale);
      uu.u[3] = cvt_pk_bf16(y.z * qscale, y.w * qscale);
      qf[dc] = uu.v;
    }
  }

  f32x16 oacc[4];
#pragma unroll
  for (int gg = 0; gg < 4; ++gg)
#pragma unroll
    for (int r = 0; r < 16; ++r) oacc[gg][r] = 0.f;

  float mrun = -1e30f, lrun = 0.f;
  const unsigned char* mrow8  = M8 + ((size_t)b * 2048 + q) * (size_t)2048;
  const int*           mrow32 = (const int*)M8 + ((size_t)b * 2048 + q) * (size_t)2048;
  const int xk = 8 * (l31 & 15);
  const int xv = 8 * (l31 >> 2);
  const char* imgb = img + (size_t)(b * 32) * 32768;
  const int wb4 = wv * 4096;            // this wave's 4KB slice of each 16KB seg

#define DMAK(t_, slot_)                                                                          \
  do {                                                                                            \
    const char* s_ = imgb + (size_t)(t_) * 32768 + wb4;                                           \
    char* d_ = (char*)&Kl[slot_][0] + wb4;                                                        \
    _Pragma("unroll")                                                                             \
    for (int j_ = 0; j_ < 4; ++j_)                                                                \
      __builtin_amdgcn_global_load_lds((const GAS unsigned*)(s_ + j_ * 1024 + lane * 16),         \
                                       (LAS unsigned*)(d_ + j_ * 1024), 16, 0, 0);                \
  } while (0)
#define DMAV(t_, slot_)                                                                           \
  do {                                                                                            \
    const char* s_ = imgb + (size_t)(t_) * 32768 + 16384 + wb4;                                   \
    char* d_ = (char*)&Vt[slot_][0] + wb4;                                                        \
    _Pragma("unroll")                                                                             \
    for (int j_ = 0; j_ < 4; ++j_)                                                                \
      __builtin_amdgcn_global_load_lds((const GAS unsigned*)(s_ + j_ * 1024 + lane * 16),         \
                                       (LAS unsigned*)(d_ + j_ * 1024), 16, 0, 0);                \
  } while (0)

#define QK18(slot_, s0_, s1_)                                                        \
  do {                                                                                \
    const short* klb_ = &Kl[slot_][0];                                                \
    _Pragma("unroll")                                                                 \
    for (int r = 0; r < 16; ++r) { (s0_)[r] = 0.f; (s1_)[r] = 0.f; }                  \
    _Pragma("unroll")                                                                 \
    for (int dc = 0; dc < 8; ++dc) {                                                  \
      const int colb_ = (dc * 16 + hi * 8) ^ xk;                                      \
      bf16x8 a0_ = *(const bf16x8*)&klb_[l31 * 128 + colb_];                          \
      bf16x8 a1_ = *(const bf16x8*)&klb_[(32 + l31) * 128 + colb_];                   \
      (s0_) = __builtin_amdgcn_mfma_f32_32x32x16_bf16(a0_, qf[dc], (s0_), 0, 0, 0);   \
      (s1_) = __builtin_amdgcn_mfma_f32_32x32x16_bf16(a1_, qf[dc], (s1_), 0, 0, 0);   \
    }                                                                                 \
  } while (0)

  // ---- prologue: K0, V0, K1; drain; QK(0); BARRIER (race fix) ----
  DMAK(0, 0);
  DMAV(0, 0);
  DMAK(1, 1);
  __syncthreads();

  f32x16 s0A, s1A, s0B, s1B;
  QK18(0, s0A, s1A);
  __syncthreads();   // all waves done reading K slot 0 before iter-0 DMAK(2,0)

  for (int kt = 0; kt < 32; ++kt) {
    // ---- DMA K(kt+2) into dead K slot, V(kt+1) into dead V slot ----
    if (kt < 30) DMAK(kt + 2, kt & 1);
    if (kt < 31) DMAV(kt + 1, (kt + 1) & 1);

    // ---- this tile's mask dwords ----
    unsigned mg[8];
    if (is8) {
#pragma unroll
      for (int m = 0; m < 4; ++m) {
        mg[m]     = *(const unsigned*)(mrow8 + kt * 64 + hi * 4 + m * 8);
        mg[4 + m] = *(const unsigned*)(mrow8 + kt * 64 + 32 + hi * 4 + m * 8);
      }
    }

    // ---- QK(kt+1): independent MFMA stream, overlaps softmax below ----
    if (kt < 31) {
      __builtin_amdgcn_s_setprio(1);
      QK18((kt + 1) & 1, s0B, s1B);
      __builtin_amdgcn_s_setprio(0);
    }

    // ---- mask tile kt: reg r <-> k = 32*kk + (r&3) + 8*(r>>2) + 4*hi ----
    if (is8) {
#pragma unroll
      for (int m = 0; m < 4; ++m)
#pragma unroll
        for (int e = 0; e < 4; ++e) {
          s0A[4 * m + e] = ((mg[m]     >> (8 * e)) & 0xffu) ? MASKV2 : s0A[4 * m + e];
          s1A[4 * m + e] = ((mg[4 + m] >> (8 * e)) & 0xffu) ? MASKV2 : s1A[4 * m + e];
        }
    } else {
#pragma unroll
      for (int m = 0; m < 4; ++m) {
        int4 w0 = *(const int4*)(mrow32 + kt * 64 + hi * 4 + m * 8);
        int4 w1 = *(const int4*)(mrow32 + kt * 64 + 32 + hi * 4 + m * 8);
        s0A[4 * m + 0] = w0.x ? MASKV2 : s0A[4 * m + 0];
        s0A[4 * m + 1] = w0.y ? MASKV2 : s0A[4 * m + 1];
        s0A[4 * m + 2] = w0.z ? MASKV2 : s0A[4 * m + 2];
        s0A[4 * m + 3] = w0.w ? MASKV2 : s0A[4 * m + 3];
        s1A[4 * m + 0] = w1.x ? MASKV2 : s1A[4 * m + 0];
        s1A[4 * m + 1] = w1.y ? MASKV2 : s1A[4 * m + 1];
        s1A[4 * m + 2] = w1.z ? MASKV2 : s1A[4 * m + 2];
        s1A[4 * m + 3] = w1.w ? MASKV2 : s1A[4 * m + 3];
      }
    }

    // ---- online softmax (tree in-lane + verified shfl cross-half) ----
    float v[16];
#pragma unroll
    for (int r = 0; r < 16; ++r) v[r] = fmaxf(s0A[r], s1A[r]);
#pragma unroll
    for (int st = 8; st > 0; st >>= 1)
#pragma unroll
      for (int r = 0; r < 8; ++r)
        if (r < st) v[r] = fmaxf(v[r], v[r + st]);
    float tm = fmaxf(v[0], __shfl_xor(v[0], 32));

    if (__any(tm > mrun + 8.0f)) {        // defer-max (T13)
      float mnew = fmaxf(mrun, tm);
      float corr = __builtin_amdgcn_exp2f(mrun - mnew);
      mrun = mnew; lrun *= corr;
#pragma unroll
      for (int gg = 0; gg < 4; ++gg)
#pragma unroll
        for (int r = 0; r < 16; ++r) oacc[gg][r] *= corr;
    }

#pragma unroll
    for (int r = 0; r < 16; ++r) s0A[r] = __builtin_amdgcn_exp2f(s0A[r] - mrun);
#pragma unroll
    for (int r = 0; r < 16; ++r) s1A[r] = __builtin_amdgcn_exp2f(s1A[r] - mrun);
    float w[16];
#pragma unroll
    for (int r = 0; r < 16; ++r) w[r] = s0A[r] + s1A[r];
#pragma unroll
    for (int st = 8; st > 0; st >>= 1)
#pragma unroll
      for (int r = 0; r < 8; ++r)
        if (r < st) w[r] += w[r + st];
    lrun += w[0] + __shfl_xor(w[0], 32);

    // ---- P (S^T C-layout) -> P^T B-frags (verified shfl path) ----
    unsigned pk0[8], pk1[8];
#pragma unroll
    for (int i = 0; i < 8; ++i) {
      pk0[i] = cvt_pk_bf16(s0A[2 * i], s0A[2 * i + 1]);
      pk1[i] = cvt_pk_bf16(s1A[2 * i], s1A[2 * i + 1]);
    }
    bf16x8 pa[4];
#pragma unroll
    for (int ks = 0; ks < 4; ++ks) {
      const int base = 4 * (ks & 1);
      unsigned o0, o1, sd0, sd1;
      if (ks < 2) {
        o0  = hi ? pk0[base + 2] : pk0[base + 0];
        o1  = hi ? pk0[base + 3] : pk0[base + 1];
        sd0 = hi ? pk0[base + 0] : pk0[base + 2];
        sd1 = hi ? pk0[base + 1] : pk0[base + 3];
      } else {
        o0  = hi ? pk1[base + 2] : pk1[base + 0];
        o1  = hi ? pk1[base + 3] : pk1[base + 1];
        sd0 = hi ? pk1[base + 0] : pk1[base + 2];
        sd1 = hi ? pk1[base + 1] : pk1[base + 3];
      }
      unsigned rec0 = (unsigned)__shfl_xor((int)sd0, 32);
      unsigned rec1 = (unsigned)__shfl_xor((int)sd1, 32);
      union { bf16x8 v; unsigned u[4]; } uu;
      uu.u[0] = hi ? rec0 : o0;
      uu.u[1] = hi ? rec1 : o1;
      uu.u[2] = hi ? o0 : rec0;
      uu.u[3] = hi ? o1 : rec1;
      pa[ks] = uu.v;
    }

    // ---- O^T += V^T · P^T (V from slot kt&1) ----
    {
      const short* vtb = &Vt[kt & 1][0];
      __builtin_amdgcn_s_setprio(1);
#pragma unroll
      for (int gg = 0; gg < 4; ++gg) {
        const int drow = gg * 32 + l31;
#pragma unroll
        for (int ks = 0; ks < 4; ++ks) {
          bf16x8 va = *(const bf16x8*)&vtb[drow * 64 + ((ks * 16 + hi * 8) ^ xv)];
          oacc[gg] = __builtin_amdgcn_mfma_f32_32x32x16_bf16(va, pa[ks], oacc[gg], 0, 0, 0);
        }
      }
      __builtin_amdgcn_s_setprio(0);
    }

    // ---- rotate S pipeline ----
    if (kt < 31) { s0A = s0B; s1A = s1B; }

    __syncthreads();   // drains vmcnt(0): K(kt+2) and V(kt+1) ready
  }
#undef DMAK
#undef DMAV
#undef QK18

  // ---- epilogue: O[q][d] = oacc/l; d = 32gg + 4hi + 8m + e ----
  const float inv = 1.0f / lrun;
  float* orow = Op + ((size_t)b * 2048 + q) * 128;
#pragma unroll
  for (int gg = 0; gg < 4; ++gg) {
#pragma unroll
    for (int m = 0; m < 4; ++m) {
      float4 o;
      o.x = oacc[gg][4 * m + 0] * inv;
      o.y = oacc[gg][4 * m + 1] * inv;
      o.z = oacc[gg][4 * m + 2] * inv;
      o.w = oacc[gg][4 * m + 3] * inv;
      *(float4*)(orow + gg * 32 + hi * 4 + m * 8) = o;
    }
  }
}

// Fallback (ws too small): r5's reg-staged kernel, verified shfl path.
__global__ __launch_bounds__(512, 2)
void attn_fb(const float* __restrict__ Qp, const float* __restrict__ Kp,
             const float* __restrict__ Vp, const unsigned char* __restrict__ M8,
             float* __restrict__ Op, const int* __restrict__ flag)
{
  const int tid  = threadIdx.x;
  const int lane = tid & 63;
  const int wv   = tid >> 6;
  const int hi   = lane >> 5;
  const int l31  = lane & 31;
  const int n    = blockIdx.x;
  const int b    = (n & 7) + 8 * (n >> 6);
  const int qt   = (n >> 3) & 7;
  const int q    = qt * 256 + wv * 32 + l31;
  const bool is8 = (flag[0] != 0);

  __shared__ __align__(16) short Kl[2][64 * 128];
  __shared__ __align__(16) short Vt[2][128 * 64];

  const float qscale = 0.08838834764831845f * LOG2E;
  bf16x8 qf[8];
  {
    const float* qrow = Qp + ((size_t)b * 2048 + q) * 128;
#pragma unroll
    for (int dc = 0; dc < 8; ++dc) {
      const int d0 = dc * 16 + hi * 8;
      float4 x = *(const float4*)(qrow + d0);
      float4 y = *(const float4*)(qrow + d0 + 4);
      union { bf16x8 v; unsigned u[4]; } uu;
      uu.u[0] = cvt_pk_bf16(x.x * qscale, x.y * qscale);
      uu.u[1] = cvt_pk_bf16(x.z * qscale, x.w * qscale);
      uu.u[2] = cvt_pk_bf16(y.x * qscale, y.y * qscale);
      uu.u[3] = cvt_pk_bf16(y.z * qscale, y.w * qscale);
      qf[dc] = uu.v;
    }
  }
  f32x16 oacc[4];
#pragma unroll
  for (int gg = 0; gg < 4; ++gg)
#pragma unroll
    for (int r = 0; r < 16; ++r) oacc[gg][r] = 0.f;
  float mrun = -1e30f, lrun = 0.f;
  const unsigned char* mrow8  = M8 + ((size_t)b * 2048 + q) * (size_t)2048;
  const int*           mrow32 = (const int*)M8 + ((size_t)b * 2048 + q) * (size_t)2048;
  const int xk = 8 * (l31 & 15);
  const int xv = 8 * (l31 >> 2);
  const int db = tid & 31, kb = tid >> 5;
  const size_t kvrow0 = (size_t)b * 2048 * 128;
  const int krow0 = tid >> 5, kcol0 = (tid & 31) * 4;

  {
#pragma unroll
    for (int i = 0; i < 4; ++i) {
      const int row = krow0 + i * 16;
      float4 x = *(const float4*)(Kp + kvrow0 + row * 128 + kcol0);
      union { s16x4 v; unsigned u[2]; } pk;
      pk.u[0] = cvt_pk_bf16(x.x, x.y);
      pk.u[1] = cvt_pk_bf16(x.z, x.w);
      *(s16x4*)&Kl[0][row * 128 + (kcol0 ^ (8 * (row & 15)))] = pk.v;
    }
    union { float4 v; float f[4]; } r0, r1, r2, r3;
    r0.v = *(const float4*)(Vp + kvrow0 + (kb * 4 + 0) * 128 + db * 4);
    r1.v = *(const float4*)(Vp + kvrow0 + (kb * 4 + 1) * 128 + db * 4);
    r2.v = *(const float4*)(Vp + kvrow0 + (kb * 4 + 2) * 128 + db * 4);
    r3.v = *(const float4*)(Vp + kvrow0 + (kb * 4 + 3) * 128 + db * 4);
    const int cs = (kb * 4) ^ (8 * (db & 7));
#pragma unroll
    for (int j = 0; j < 4; ++j) {
      union { s16x4 v; unsigned u[2]; } pk;
      pk.u[0] = cvt_pk_bf16(r0.f[j], r1.f[j]);
      pk.u[1] = cvt_pk_bf16(r2.f[j], r3.f[j]);
      *(s16x4*)&Vt[0][(db * 4 + j) * 64 + cs] = pk.v;
    }
  }
  __syncthreads();

  for (int kt = 0; kt < 32; ++kt) {
    const int cur = kt & 1;
    const short* klb = &Kl[cur][0];
    const short* vtb = &Vt[cur][0];
    const int ktn = (kt < 31) ? kt + 1 : 31;
    const size_t nb = kvrow0 + (size_t)ktn * 64 * 128;
    float4 kreg[4], vreg[4];
#pragma unroll
    for (int i = 0; i < 4; ++i)
      kreg[i] = *(const float4*)(Kp + nb + (krow0 + i * 16) * 128 + kcol0);
#pragma unroll
    for (int i = 0; i < 4; ++i)
      vreg[i] = *(const float4*)(Vp + nb + (kb * 4 + i) * 128 + db * 4);

    f32x16 s0m, s1m;
#pragma unroll
    for (int r = 0; r < 16; ++r) { s0m[r] = 0.f; s1m[r] = 0.f; }
#pragma unroll
    for (int dc = 0; dc < 8; ++dc) {
      const int colb = (dc * 16 + hi * 8) ^ xk;
      bf16x8 a0 = *(const bf16x8*)&klb[l31 * 128 + colb];
      bf16x8 a1 = *(const bf16x8*)&klb[(32 + l31) * 128 + colb];
      s0m = __builtin_amdgcn_mfma_f32_32x32x16_bf16(a0, qf[dc], s0m, 0, 0, 0);
      s1m = __builtin_amdgcn_mfma_f32_32x32x16_bf16(a1, qf[dc], s1m, 0, 0, 0);
    }
    if (is8) {
#pragma unroll
      for (int m = 0; m < 4; ++m) {
        unsigned w0 = *(const unsigned*)(mrow8 + kt * 64 + hi * 4 + m * 8);
        unsigned w1 = *(const unsigned*)(mrow8 + kt * 64 + 32 + hi * 4 + m * 8);
#pragma unroll
        for (int e = 0; e < 4; ++e) {
          s0m[4 * m + e] = ((w0 >> (8 * e)) & 0xffu) ? MASKV2 : s0m[4 * m + e];
          s1m[4 * m + e] = ((w1 >> (8 * e)) & 0xffu) ? MASKV2 : s1m[4 * m + e];
        }
      }
    } else {
#pragma unroll
      for (int m = 0; m < 4; ++m) {
        int4 w0 = *(const int4*)(mrow32 + kt * 64 + hi * 4 + m * 8);
        int4 w1 = *(const int4*)(mrow32 + kt * 64 + 32 + hi * 4 + m * 8);
        s0m[4 * m + 0] = w0.x ? MASKV2 : s0m[4 * m + 0];
        s0m[4 * m + 1] = w0.y ? MASKV2 : s0m[4 * m + 1];
        s0m[4 * m + 2] = w0.z ? MASKV2 : s0m[4 * m + 2];
        s0m[4 * m + 3] = w0.w ? MASKV2 : s0m[4 * m + 3];
        s1m[4 * m + 0] = w1.x ? MASKV2 : s1m[4 * m + 0];
        s1m[4 * m + 1] = w1.y ? MASKV2 : s1m[4 * m + 1];
        s1m[4 * m + 2] = w1.z ? MASKV2 : s1m[4 * m + 2];
        s1m[4 * m + 3] = w1.w ? MASKV2 : s1m[4 * m + 3];
      }
    }
    float tm = s0m[0];
#pragma unroll
    for (int r = 1; r < 16; ++r) tm = fmaxf(tm, s0m[r]);
#pragma unroll
    for (int r = 0; r < 16; ++r) tm = fmaxf(tm, s1m[r]);
    tm = fmaxf(tm, __shfl_xor(tm, 32));
    if (__any(tm > mrun + 8.0f)) {
      float mnew = fmaxf(mrun, tm);
      float corr = __builtin_amdgcn_exp2f(mrun - mnew);
      mrun = mnew; lrun *= corr;
#pragma unroll
      for (int gg = 0; gg < 4; ++gg)
#pragma unroll
        for (int r = 0; r < 16; ++r) oacc[gg][r] *= corr;
    }
    float psum = 0.f;
#pragma unroll
    for (int r = 0; r < 16; ++r) { s0m[r] = __builtin_amdgcn_exp2f(s0m[r] - mrun); psum += s0m[r]; }
#pragma unroll
    for (int r = 0; r < 16; ++r) { s1m[r] = __builtin_amdgcn_exp2f(s1m[r] - mrun); psum += s1m[r]; }
    psum += __shfl_xor(psum, 32);
    lrun += psum;
    unsigned pk0[8], pk1[8];
#pragma unroll
    for (int i = 0; i < 8; ++i) {
      pk0[i] = cvt_pk_bf16(s0m[2 * i], s0m[2 * i + 1]);
      pk1[i] = cvt_pk_bf16(s1m[2 * i], s1m[2 * i + 1]);
    }
    bf16x8 pa[4];
#pragma unroll
    for (int ks = 0; ks < 4; ++ks) {
      const int base = 4 * (ks & 1);
      unsigned o0, o1, sd0, sd1;
      if (ks < 2) {
        o0  = hi ? pk0[base + 2] : pk0[base + 0];
        o1  = hi ? pk0[base + 3] : pk0[base + 1];
        sd0 = hi ? pk0[base + 0] : pk0[base + 2];
        sd1 = hi ? pk0[base + 1] : pk0[base + 3];
      } else {
        o0  = hi ? pk1[base + 2] : pk1[base + 0];
        o1  = hi ? pk1[base + 3] : pk1[base + 1];
        sd0 = hi ? pk1[base + 0] : pk1[base + 2];
        sd1 = hi ? pk1[base + 1] : pk1[base + 3];
      }
      unsigned rec0 = (unsigned)__shfl_xor((int)sd0, 32);
      unsigned rec1 = (unsigned)__shfl_xor((int)sd1, 32);
      union { bf16x8 v; unsigned u[4]; } uu;
      uu.u[0] = hi ? rec0 : o0;
      uu.u[1] = hi ? rec1 : o1;
      uu.u[2] = hi ? o0 : rec0;
      uu.u[3] = hi ? o1 : rec1;
      pa[ks] = uu.v;
    }
#pragma unroll
    for (int gg = 0; gg < 4; ++gg) {
      const int drow = gg * 32 + l31;
#pragma unroll
      for (int ks = 0; ks < 4; ++ks) {
        bf16x8 va = *(const bf16x8*)&vtb[drow * 64 + ((ks * 16 + hi * 8) ^ xv)];
        oacc[gg] = __builtin_amdgcn_mfma_f32_32x32x16_bf16(va, pa[ks], oacc[gg], 0, 0, 0);
      }
    }
    {
      short* kln = &Kl[cur ^ 1][0];
      short* vtn = &Vt[cur ^ 1][0];
#pragma unroll
      for (int i = 0; i < 4; ++i) {
        const int row = krow0 + i * 16;
        union { s16x4 v; unsigned u[2]; } pk;
        pk.u[0] = cvt_pk_bf16(kreg[i].x, kreg[i].y);
        pk.u[1] = cvt_pk_bf16(kreg[i].z, kreg[i].w);
        *(s16x4*)&kln[row * 128 + (kcol0 ^ (8 * (row & 15)))] = pk.v;
      }
      const int cs = (kb * 4) ^ (8 * (db & 7));
#pragma unroll
      for (int j = 0; j < 4; ++j) {
        union { s16x4 v; unsigned u[2]; } pk;
        union { float4 v; float f[4]; } a0, a1, a2, a3;
        a0.v = vreg[0]; a1.v = vreg[1]; a2.v = vreg[2]; a3.v = vreg[3];
        pk.u[0] = cvt_pk_bf16(a0.f[j], a1.f[j]);
        pk.u[1] = cvt_pk_bf16(a2.f[j], a3.f[j]);
        *(s16x4*)&vtn[(db * 4 + j) * 64 + cs] = pk.v;
      }
    }
    __syncthreads();
  }
  const float inv = 1.0f / lrun;
  float* orow = Op + ((size_t)b * 2048 + q) * 128;
#pragma unroll
  for (int gg = 0; gg < 4; ++gg) {
#pragma unroll
    for (int m = 0; m < 4; ++m) {
      float4 o;
      o.x = oacc[gg][4 * m + 0] * inv;
      o.y = oacc[gg][4 * m + 1] * inv;
      o.z = oacc[gg][4 * m + 2] * inv;
      o.w = oacc[gg][4 * m + 3] * inv;
      *(float4*)(orow + gg * 32 + hi * 4 + m * 8) = o;
    }
  }
}

extern "C" void kernel_launch(void* const* d_in, const int* in_sizes, int n_in,
                              void* d_out, int out_size, void* d_ws, size_t ws_size,
                              hipStream_t stream) {
  const float* qp = (const float*)d_in[0];
  const float* kp = (const float*)d_in[1];
  const float* vp = (const float*)d_in[2];
  const unsigned char* mp = (const unsigned char*)d_in[3];
  float* op = (float*)d_out;
  int* flag = (int*)d_ws;

  detect_mask_kernel<<<1, 256, 0, stream>>>(mp, flag);

  const size_t need = 256 + (size_t)1024 * 32768;   // 32 MB of tile images
  if (ws_size >= need) {
    char* img = (char*)d_ws + 256;
    build_images<<<1024, 512, 0, stream>>>(kp, vp, img);
    attn18<<<512, 256, 0, stream>>>(qp, mp, img, op, flag);
  } else {
    attn_fb<<<256, 512, 0, stream>>>(qp, kp, vp, mp, op, flag);
  }
}